// Round 6
// baseline (505.670 us; speedup 1.0000x reference)
//
#include <hip/hip_runtime.h>

typedef unsigned short u16;
typedef short bf16x8 __attribute__((ext_vector_type(8)));
typedef float f32x4 __attribute__((ext_vector_type(4)));
typedef unsigned short u16x4 __attribute__((ext_vector_type(4)));

typedef const __attribute__((address_space(1))) unsigned int* gas_ptr;
typedef __attribute__((address_space(3))) unsigned int* las_ptr;

__device__ __forceinline__ void gl_lds16(const void* g, void* l) {
  // async 16B/lane global->LDS; lds dest = wave-uniform base + lane*16
  __builtin_amdgcn_global_load_lds((gas_ptr)g, (las_ptr)l, 16, 0, 0);
}

__device__ __forceinline__ u16 f2bf(float f) {
  union { float f; unsigned u; } v; v.f = f;
  unsigned r = v.u + 0x7FFFu + ((v.u >> 16) & 1u);
  return (u16)(r >> 16);
}

__device__ __forceinline__ float fexp2(float x) {  // single v_exp_f32 (exp2)
  float r; asm("v_exp_f32 %0, %1" : "=v"(r) : "v"(x)); return r;
}

__device__ __forceinline__ unsigned cvt_pk_bf16(float lo, float hi) {
  unsigned r;
  asm("v_cvt_pk_bf16_f32 %0, %1, %2" : "=v"(r) : "v"(lo), "v"(hi));
  return r;
}

__device__ __forceinline__ float swap1(float x) {
  // lane^1 exchange via DPP quad_perm [1,0,3,2] -- 1 VALU op, no LDS pipe
  int i = __builtin_amdgcn_mov_dpp(__float_as_int(x), 0xB1, 0xF, 0xF, true);
  return __int_as_float(i);
}

// ---------------- convert fp32 -> bf16 (hs, Wqkv, Wo) + RoPE tables --------
// blocks [0,8192): 4 elems/thread conversion; blocks [8192,8448): rope tables
__global__ void k_convert(const float* __restrict__ hs, const float* __restrict__ Wq,
                          const float* __restrict__ Wk, const float* __restrict__ Wv,
                          const float* __restrict__ Wo,
                          u16* __restrict__ Xb, u16* __restrict__ Wqkv, u16* __restrict__ Wob,
                          float* __restrict__ ctab, float* __restrict__ stab) {
  if (blockIdx.x >= 8192) {   // 2048 x 32 tables, double precision
    int t = (blockIdx.x - 8192) * 256 + threadIdx.x;
    int s = t >> 5, tt = t & 31;
    double f = exp(-((double)(2 * tt) / 64.0) * log(10000.0));
    double a = (double)s * f;
    ctab[t] = (float)cos(a);
    stab[t] = (float)sin(a);
    return;
  }
  int e = (blockIdx.x * 256 + threadIdx.x) * 4;
  const int R1 = 4096 * 1024, R2 = R1 + 3072 * 1024;
  float4 v; u16* dst;
  if (e < R1) {
    v = *(const float4*)&hs[e]; dst = Xb + e;
  } else if (e < R2) {
    int w = e - R1; int row = w >> 10, col = w & 1023;
    const float* src = row < 1024 ? &Wq[(size_t)row * 1024]
                     : (row < 2048 ? &Wk[(size_t)(row - 1024) * 1024]
                                   : &Wv[(size_t)(row - 2048) * 1024]);
    v = *(const float4*)&src[col]; dst = Wqkv + w;
  } else {
    int w = e - R2; v = *(const float4*)&Wo[w]; dst = Wob + w;
  }
  u16x4 o; o[0] = f2bf(v.x); o[1] = f2bf(v.y); o[2] = f2bf(v.z); o[3] = f2bf(v.w);
  *(u16x4*)dst = o;
}

// ---------------- fused QKV GEMM + RoPE + V-transpose epilogue --------------
// C[4096,3072] = Xb @ Wqkv^T; per 128x128 tile the epilogue:
//   bn<8  (Q cols): rope via DPP lane^1 pair exchange, scale 0.125*log2e -> Qb
//   bn<16 (K cols): rope, scale 1 -> Kb [B,H,S,64]
//   bn>=16 (V cols): transpose-write -> Vtb [B,H,64,S]
// XCD swizzle: chunk 4 bm-rows per XCD (768%8==0, bijective).
__global__ __launch_bounds__(256, 3)
void k_gemm_qkv(const u16* __restrict__ A, const u16* __restrict__ B,
                const float* __restrict__ ctab, const float* __restrict__ stab,
                u16* __restrict__ Qb, u16* __restrict__ Kb, u16* __restrict__ Vtb,
                int K) {
  __shared__ u16 ldsA[128 * 64];
  __shared__ u16 ldsB[128 * 64];
  const int tid = threadIdx.x;
  const int g = blockIdx.y * 24 + blockIdx.x;
  const int xcd = g & 7, gi = g >> 3;       // gi in [0,96)
  const int bm = xcd * 4 + (gi & 3);        // [0,32): 4 bm rows per XCD
  const int bn = gi >> 2;                   // [0,24)
  const int lane = tid & 63, wave = tid >> 6;
  const int wm = wave >> 1, wn = wave & 1;
  const int l16 = lane & 15, quad = lane >> 4;

  // staging: lane -> tile row (p*32 + wave*8 + l>>3), global chunk (l&7)^(l>>3)
  const int srow = lane >> 3;
  const int scol = ((lane & 7) ^ srow) * 8;
  const u16* agb = A + (size_t)(bm * 128 + wave * 8 + srow) * K + scol;
  const u16* bgb = B + (size_t)(bn * 128 + wave * 8 + srow) * K + scol;

  const f32x4 vzero = {0.f, 0.f, 0.f, 0.f};
  f32x4 acc[4][4];
#pragma unroll
  for (int i = 0; i < 4; ++i)
#pragma unroll
    for (int j = 0; j < 4; ++j) acc[i][j] = vzero;

  const int xq = l16 & 7;   // reader swizzle key (= row&7)
  const int NKT = K >> 6;
  for (int kt = 0; kt < NKT; ++kt) {
    __syncthreads();
#pragma unroll
    for (int p = 0; p < 4; ++p) {
      gl_lds16(agb + (size_t)p * 32 * K + kt * 64, &ldsA[(p * 4 + wave) * 512]);
      gl_lds16(bgb + (size_t)p * 32 * K + kt * 64, &ldsB[(p * 4 + wave) * 512]);
    }
    __syncthreads();
#pragma unroll
    for (int ks = 0; ks < 2; ++ks) {
      bf16x8 af[4], bfr[4];
#pragma unroll
      for (int mi = 0; mi < 4; ++mi)
        af[mi] = *(const bf16x8*)&ldsA[(wm * 64 + mi * 16 + l16) * 64 + ((ks * 4 + quad) ^ xq) * 8];
#pragma unroll
      for (int ni = 0; ni < 4; ++ni)
        bfr[ni] = *(const bf16x8*)&ldsB[(wn * 64 + ni * 16 + l16) * 64 + ((ks * 4 + quad) ^ xq) * 8];
#pragma unroll
      for (int mi = 0; mi < 4; ++mi)
#pragma unroll
        for (int ni = 0; ni < 4; ++ni)
          acc[mi][ni] = __builtin_amdgcn_mfma_f32_16x16x32_bf16(af[mi], bfr[ni], acc[mi][ni], 0, 0, 0);
    }
  }

  const int row0 = bm * 128 + wm * 64, col0 = bn * 128 + wn * 64;
  const int sect = bn >> 3;  // 0=Q, 1=K, 2=V

  if (sect < 2) {
    u16* dst = sect == 0 ? Qb : Kb;
    const float mul = sect == 0 ? 0.18033688f : 1.0f;   // 0.125 * log2(e)
#pragma unroll
    for (int mi = 0; mi < 4; ++mi)
#pragma unroll
      for (int ni = 0; ni < 4; ++ni) {
        int col = col0 + ni * 16 + l16;
        int cc = col & 1023;
        int h = cc >> 6, tt = (cc & 63) >> 1;
#pragma unroll
        for (int rr = 0; rr < 4; ++rr) {
          int row = row0 + mi * 16 + quad * 4 + rr;
          int s = row & 2047, bb = row >> 11;
          float x = acc[mi][ni][rr];
          float xo = swap1(x);             // neighbor col's value (DPP, no LDS)
          float x1 = (l16 & 1) ? xo : x;   // even-col element
          float x2 = (l16 & 1) ? x : xo;   // odd-col element
          float cs = ctab[s * 32 + tt], sn = stab[s * 32 + tt];
          float r1 = (x1 * cs - x2 * sn) * mul;
          float r2 = (x1 * sn + x2 * cs) * mul;
          if (!(l16 & 1)) {
            union { u16 h2[2]; unsigned u; } o;
            o.h2[0] = f2bf(r1); o.h2[1] = f2bf(r2);
            *(unsigned*)&dst[((size_t)(bb * 16 + h) * 2048 + s) * 64 + (cc & 63)] = o.u;
          }
        }
      }
  } else {
    // V: per lane, acc[mi][ni][0..3] = 4 consecutive s for fixed col -> 8B store
#pragma unroll
    for (int mi = 0; mi < 4; ++mi)
#pragma unroll
      for (int ni = 0; ni < 4; ++ni) {
        int col = col0 + ni * 16 + l16;
        int cc = col & 1023;
        int h = cc >> 6, d = cc & 63;
        int row = row0 + mi * 16 + quad * 4;
        int s = row & 2047, bb = row >> 11;
        u16x4 o;
        o[0] = f2bf(acc[mi][ni][0]); o[1] = f2bf(acc[mi][ni][1]);
        o[2] = f2bf(acc[mi][ni][2]); o[3] = f2bf(acc[mi][ni][3]);
        *(u16x4*)&Vtb[((size_t)(bb * 16 + h) * 64 + d) * 2048 + s] = o;
      }
  }
}

// ---------------- flash attention v10: QBLK=128, DPP pair-pack P -------------
// R5 accounting: attn ~143us vs ~66us LDS-pipe floor (309 cy/wave-tile).
// This round: P-store via DPP lane^1 (VALU, not ds_bpermute -- R2's mistake)
// + v_cvt_pk_bf16_f32 + even-lane ds_write_b32:
//   16 b16 writes -> 8 b32 writes per wave-tile (LDS floor 66 -> ~56us)
//   16x f2bf (~64 VALU) -> 8x cvt_pk + 16 DPP movs
// __launch_bounds__(512,4): VGPR cap 128, no spill (R4 lesson: (512,6) cap 85
// spilled acc+bias to scratch -> 311MB scratch writes, 656us).
__global__ __launch_bounds__(512, 4)
void k_attn(const u16* __restrict__ Qb, const u16* __restrict__ Kb, const u16* __restrict__ Vtb,
            const float* __restrict__ rel_bias, const int* __restrict__ mask,
            u16* __restrict__ Ob) {
  __shared__ u16 Ks[2][64 * 64];
  __shared__ u16 Vs[2][64 * 64];
  __shared__ u16 Ps[128 * 64];   // XOR-swizzled like Ks/Vs; wave w owns rows w*16..+15

  const int tid = threadIdx.x;
  const int gid = blockIdx.x;
  const int h = gid & 15, b = (gid >> 4) & 1, qt = gid >> 5;  // qt in [0,16)
  const int bh = b * 16 + h;
  const int lane = tid & 63, w = tid >> 6;                    // w in [0,8)
  const int l16 = lane & 15, quad = lane >> 4;
  const int xq = l16 & 7;   // reader swizzle key (= row&7 for rows ...+l16)

  // Q fragments in registers (rows qt*128 + w*16 + l16), direct global
  bf16x8 qreg[2];
  {
    const u16* qg = Qb + ((size_t)bh * 2048 + qt * 128 + w * 16 + l16) * 64 + quad * 8;
    qreg[0] = *(const bf16x8*)&qg[0];
    qreg[1] = *(const bf16x8*)&qg[32];
  }

  // staging: 8 waves cover 64 rows in one pass; lane -> row w*8 + l>>3,
  // global chunk (l&7)^(l>>3) (pre-swizzled source, linear LDS dest)
  const int srow = lane >> 3;
  const int scol = ((lane & 7) ^ srow) * 8;
  const u16* kgb = Kb + ((size_t)bh * 2048 + w * 8 + srow) * 64 + scol;
  const u16* vgb = Vtb + ((size_t)bh * 64 + w * 8 + srow) * 2048 + scol;

  // bias/mask bases: rows quad*4+rr, col l16 (+ kt0 + ni*16)
  const float* bp[4];
#pragma unroll
  for (int rr = 0; rr < 4; ++rr)
    bp[rr] = rel_bias + ((size_t)h * 2048 + qt * 128 + w * 16 + quad * 4 + rr) * 2048 + l16;
  const int* mbase = mask + b * 2048 + l16;

  const f32x4 vzero = {0.f, 0.f, 0.f, 0.f};
  f32x4 accO[4];
  float ls[4] = {0.f, 0.f, 0.f, 0.f};
#pragma unroll
  for (int ni = 0; ni < 4; ++ni) accO[ni] = vzero;

  // prologue: bias tile 0 (pre-transformed to exp2 domain) + DMA tile 0
  float brc[4][4], brn[4][4];
#pragma unroll
  for (int ni = 0; ni < 4; ++ni) {
    int mk = mbase[ni * 16];
#pragma unroll
    for (int rr = 0; rr < 4; ++rr) {
      float bv = bp[rr][ni * 16];
      brc[ni][rr] = mk ? bv * 1.44269504f - 34.6246810f : -1e30f;
    }
  }
  gl_lds16(kgb, &Ks[0][w * 512]);
  gl_lds16(vgb, &Vs[0][w * 512]);

  for (int t = 0; t < 32; ++t) {
    const int cur = t & 1, nxt = cur ^ 1;
    const int kt0 = t * 64;
    // Single barrier: (a) drains this wave's DMA(t) [issued last iter, covered
    // by tile t-1 compute], (b) all waves done reading buf[nxt] in tile t-1.
    __syncthreads();

    if (t + 1 < 32) {  // issue t+1 DMA + bias: in flight across the WHOLE tile t
      gl_lds16(kgb + (kt0 + 64) * 64, &Ks[nxt][w * 512]);
      gl_lds16(vgb + kt0 + 64,        &Vs[nxt][w * 512]);
#pragma unroll
      for (int ni = 0; ni < 4; ++ni) {
        int mk = mbase[kt0 + 64 + ni * 16];
#pragma unroll
        for (int rr = 0; rr < 4; ++rr) {
          float bv = bp[rr][kt0 + 64 + ni * 16];
          brn[ni][rr] = mk ? bv * 1.44269504f - 34.6246810f : -1e30f;
        }
      }
    }

    // S2 = (Q K^T)*0.125*log2e on buf[cur]
    f32x4 sa[4];
#pragma unroll
    for (int ni = 0; ni < 4; ++ni) sa[ni] = vzero;
    __builtin_amdgcn_s_setprio(1);
#pragma unroll
    for (int ks = 0; ks < 2; ++ks) {
#pragma unroll
      for (int ni = 0; ni < 4; ++ni) {
        bf16x8 kf = *(const bf16x8*)&Ks[cur][(ni * 16 + l16) * 64 + ((ks * 4 + quad) ^ xq) * 8];
        sa[ni] = __builtin_amdgcn_mfma_f32_16x16x32_bf16(qreg[ks], kf, sa[ni], 0, 0, 0);
      }
    }
    __builtin_amdgcn_s_setprio(0);

    // p = exp2(s2 + b2); lane-local l partials; pair-pack via DPP lane^1 +
    // cvt_pk; even lanes write b32 (cols l16, l16+1 share a 16B chunk since
    // l16&7 is even). Same swizzled layout as before, half the LDS writes.
#pragma unroll
    for (int ni = 0; ni < 4; ++ni) {
#pragma unroll
      for (int rr = 0; rr < 4; ++rr) {
        float p = fexp2(sa[ni][rr] + brc[ni][rr]);
        ls[rr] += p;
        float po = swap1(p);                 // neighbor col's value (DPP)
        if (!(l16 & 1)) {
          unsigned u = cvt_pk_bf16(p, po);   // (even,odd) cols packed
          int prow = w * 16 + quad * 4 + rr;
          int chunk = (ni * 2 + (l16 >> 3)) ^ (prow & 7);
          *(unsigned*)&Ps[prow * 64 + chunk * 8 + (l16 & 7)] = u;
        }
      }
    }
    // no barrier: Ps rows w*16..w*16+15 are written and read by wave w only

    // O += P V on buf[cur]
    __builtin_amdgcn_s_setprio(1);
#pragma unroll
    for (int ks = 0; ks < 2; ++ks) {
      bf16x8 pf = *(const bf16x8*)&Ps[(w * 16 + l16) * 64 + ((ks * 4 + quad) ^ xq) * 8];
#pragma unroll
      for (int ni = 0; ni < 4; ++ni) {
        bf16x8 vf = *(const bf16x8*)&Vs[cur][(ni * 16 + l16) * 64 + ((ks * 4 + quad) ^ xq) * 8];
        accO[ni] = __builtin_amdgcn_mfma_f32_16x16x32_bf16(pf, vf, accO[ni], 0, 0, 0);
      }
    }
    __builtin_amdgcn_s_setprio(0);

    // rotate prefetched bias (t=31: dead values, unused)
#pragma unroll
    for (int ni = 0; ni < 4; ++ni)
#pragma unroll
      for (int rr = 0; rr < 4; ++rr) brc[ni][rr] = brn[ni][rr];
  }

  // reduce l across the 16 lanes holding each row's columns, then write O
#pragma unroll
  for (int rr = 0; rr < 4; ++rr) {
#pragma unroll
    for (int d = 1; d < 16; d <<= 1) ls[rr] += __shfl_xor(ls[rr], d, 16);
  }
#pragma unroll
  for (int rr = 0; rr < 4; ++rr) {
    float inv = 1.f / ls[rr];
    int row = qt * 128 + w * 16 + quad * 4 + rr;
#pragma unroll
    for (int ni = 0; ni < 4; ++ni)
      Ob[(((size_t)b * 2048 + row) * 16 + h) * 64 + ni * 16 + l16] = f2bf(accO[ni][rr] * inv);
  }
}

// ---------------- output GEMM: 128x64 tile, XCD-chunked ---------------------
__global__ __launch_bounds__(256, 4)
void k_gemm_n64(const u16* __restrict__ A, const u16* __restrict__ B,
                const float* __restrict__ bias, float* __restrict__ C,
                int K, int ldc) {
  __shared__ u16 ldsA[128 * 64];
  __shared__ u16 ldsB[64 * 64];
  const int tid = threadIdx.x;
  const int g = blockIdx.y * 16 + blockIdx.x;
  const int xcd = g & 7, gi = g >> 3;       // gi in [0,64)
  const int bm = xcd * 4 + (gi & 3);        // [0,32)
  const int bn = gi >> 2;                   // [0,16)
  const int lane = tid & 63, wave = tid >> 6;
  const int wm = wave >> 1, wn = wave & 1;
  const int l16 = lane & 15, quad = lane >> 4;

  const int srow = lane >> 3;
  const int scol = ((lane & 7) ^ srow) * 8;
  const u16* agb = A + (size_t)(bm * 128 + wave * 8 + srow) * K + scol;
  const u16* bgb = B + (size_t)(bn * 64 + wave * 8 + srow) * K + scol;

  const f32x4 vzero = {0.f, 0.f, 0.f, 0.f};
  f32x4 acc[4][2];
#pragma unroll
  for (int i = 0; i < 4; ++i)
#pragma unroll
    for (int j = 0; j < 2; ++j) acc[i][j] = vzero;

  const int xq = l16 & 7;
  const int NKT = K >> 6;
  for (int kt = 0; kt < NKT; ++kt) {
    __syncthreads();
#pragma unroll
    for (int p = 0; p < 4; ++p)
      gl_lds16(agb + (size_t)p * 32 * K + kt * 64, &ldsA[(p * 4 + wave) * 512]);
#pragma unroll
    for (int p = 0; p < 2; ++p)
      gl_lds16(bgb + (size_t)p * 32 * K + kt * 64, &ldsB[(p * 4 + wave) * 512]);
    __syncthreads();
#pragma unroll
    for (int ks = 0; ks < 2; ++ks) {
      bf16x8 af[4], bfr[2];
#pragma unroll
      for (int mi = 0; mi < 4; ++mi)
        af[mi] = *(const bf16x8*)&ldsA[(wm * 64 + mi * 16 + l16) * 64 + ((ks * 4 + quad) ^ xq) * 8];
#pragma unroll
      for (int ni = 0; ni < 2; ++ni)
        bfr[ni] = *(const bf16x8*)&ldsB[(wn * 32 + ni * 16 + l16) * 64 + ((ks * 4 + quad) ^ xq) * 8];
#pragma unroll
      for (int mi = 0; mi < 4; ++mi)
#pragma unroll
        for (int ni = 0; ni < 2; ++ni)
          acc[mi][ni] = __builtin_amdgcn_mfma_f32_16x16x32_bf16(af[mi], bfr[ni], acc[mi][ni], 0, 0, 0);
    }
  }

  const int row0 = bm * 128 + wm * 64, col0 = bn * 64 + wn * 32;
#pragma unroll
  for (int mi = 0; mi < 4; ++mi)
#pragma unroll
    for (int ni = 0; ni < 2; ++ni) {
      int col = col0 + ni * 16 + l16;
      float badd = bias ? bias[col] : 0.f;
#pragma unroll
      for (int rr = 0; rr < 4; ++rr) {
        int row = row0 + mi * 16 + quad * 4 + rr;
        C[(size_t)row * ldc + col] = acc[mi][ni][rr] + badd;
      }
    }
}

// ---------------- launch ----------------
extern "C" void kernel_launch(void* const* d_in, const int* in_sizes, int n_in,
                              void* d_out, int out_size, void* d_ws, size_t ws_size,
                              hipStream_t stream) {
  (void)in_sizes; (void)n_in; (void)out_size; (void)ws_size;
  const float* hs  = (const float*)d_in[0];
  const int*   msk = (const int*)d_in[1];
  const float* Wq  = (const float*)d_in[2];
  const float* Wk  = (const float*)d_in[3];
  const float* Wv  = (const float*)d_in[4];
  const float* Wo  = (const float*)d_in[5];
  const float* bo  = (const float*)d_in[6];
  const float* rb  = (const float*)d_in[7];
  float* out = (float*)d_out;

  char* ws = (char*)d_ws;
  size_t off = 0;
  auto alloc = [&](size_t n) { char* p = ws + off; off += (n + 255) & ~(size_t)255; return p; };
  u16*   Xb   = (u16*)  alloc(4096UL * 1024 * 2);   // 8 MB (reused as Ob)
  u16*   Wqkv = (u16*)  alloc(3072UL * 1024 * 2);
  u16*   Wob  = (u16*)  alloc(1024UL * 1024 * 2);
  u16*   Qb   = (u16*)  alloc(4096UL * 1024 * 2);
  u16*   Kb   = (u16*)  alloc(4096UL * 1024 * 2);
  u16*   Vtb  = (u16*)  alloc(4096UL * 1024 * 2);
  float* ctab = (float*)alloc(2048UL * 32 * 4);
  float* stab = (float*)alloc(2048UL * 32 * 4);
  u16*   Ob   = Xb;  // Xb dead after fused QKV GEMM (stream-ordered)

  k_convert<<<8448, 256, 0, stream>>>(hs, Wq, Wk, Wv, Wo, Xb, Wqkv, Wob, ctab, stab);
  k_gemm_qkv<<<dim3(24, 32), 256, 0, stream>>>(Xb, Wqkv, ctab, stab, Qb, Kb, Vtb, 1024);
  k_attn<<<512, 512, 0, stream>>>(Qb, Kb, Vtb, rb, msk, Ob);
  k_gemm_n64<<<dim3(16, 32), 256, 0, stream>>>(Ob, Wob, bo, out, 1024, 1024);
}

// Round 7
// 490.940 us; speedup vs baseline: 1.0300x; 1.0300x over previous
//
#include <hip/hip_runtime.h>

typedef unsigned short u16;
typedef short bf16x8 __attribute__((ext_vector_type(8)));
typedef float f32x4 __attribute__((ext_vector_type(4)));
typedef unsigned short u16x4 __attribute__((ext_vector_type(4)));

typedef const __attribute__((address_space(1))) unsigned int* gas_ptr;
typedef __attribute__((address_space(3))) unsigned int* las_ptr;

__device__ __forceinline__ void gl_lds16(const void* g, void* l) {
  // async 16B/lane global->LDS; lds dest = wave-uniform base + lane*16
  __builtin_amdgcn_global_load_lds((gas_ptr)g, (las_ptr)l, 16, 0, 0);
}

__device__ __forceinline__ u16 f2bf(float f) {
  union { float f; unsigned u; } v; v.f = f;
  unsigned r = v.u + 0x7FFFu + ((v.u >> 16) & 1u);
  return (u16)(r >> 16);
}

__device__ __forceinline__ float fexp2(float x) {  // single v_exp_f32 (exp2)
  float r; asm("v_exp_f32 %0, %1" : "=v"(r) : "v"(x)); return r;
}

__device__ __forceinline__ float swap1(float x) {
  // lane^1 exchange via DPP quad_perm [1,0,3,2] -- 1 VALU op, no LDS pipe
  int i = __builtin_amdgcn_mov_dpp(__float_as_int(x), 0xB1, 0xF, 0xF, true);
  return __int_as_float(i);
}

// ---------------- convert fp32 -> bf16 (hs, Wqkv, Wo) + RoPE tables --------
// blocks [0,8192): 4 elems/thread conversion; blocks [8192,8448): rope tables
__global__ void k_convert(const float* __restrict__ hs, const float* __restrict__ Wq,
                          const float* __restrict__ Wk, const float* __restrict__ Wv,
                          const float* __restrict__ Wo,
                          u16* __restrict__ Xb, u16* __restrict__ Wqkv, u16* __restrict__ Wob,
                          float* __restrict__ ctab, float* __restrict__ stab) {
  if (blockIdx.x >= 8192) {   // 2048 x 32 tables, double precision
    int t = (blockIdx.x - 8192) * 256 + threadIdx.x;
    int s = t >> 5, tt = t & 31;
    double f = exp(-((double)(2 * tt) / 64.0) * log(10000.0));
    double a = (double)s * f;
    ctab[t] = (float)cos(a);
    stab[t] = (float)sin(a);
    return;
  }
  int e = (blockIdx.x * 256 + threadIdx.x) * 4;
  const int R1 = 4096 * 1024, R2 = R1 + 3072 * 1024;
  float4 v; u16* dst;
  if (e < R1) {
    v = *(const float4*)&hs[e]; dst = Xb + e;
  } else if (e < R2) {
    int w = e - R1; int row = w >> 10, col = w & 1023;
    const float* src = row < 1024 ? &Wq[(size_t)row * 1024]
                     : (row < 2048 ? &Wk[(size_t)(row - 1024) * 1024]
                                   : &Wv[(size_t)(row - 2048) * 1024]);
    v = *(const float4*)&src[col]; dst = Wqkv + w;
  } else {
    int w = e - R2; v = *(const float4*)&Wo[w]; dst = Wob + w;
  }
  u16x4 o; o[0] = f2bf(v.x); o[1] = f2bf(v.y); o[2] = f2bf(v.z); o[3] = f2bf(v.w);
  *(u16x4*)dst = o;
}

// ---------------- fused QKV GEMM + RoPE + V-transpose epilogue --------------
// C[4096,3072] = Xb @ Wqkv^T; per 128x128 tile the epilogue:
//   bn<8  (Q cols): rope via DPP lane^1 pair exchange, scale 0.125*log2e -> Qb
//   bn<16 (K cols): rope, scale 1 -> Kb [B,H,S,64]
//   bn>=16 (V cols): transpose-write -> Vtb [B,H,64,S]
// XCD swizzle: chunk 4 bm-rows per XCD (768%8==0, bijective).
__global__ __launch_bounds__(256, 3)
void k_gemm_qkv(const u16* __restrict__ A, const u16* __restrict__ B,
                const float* __restrict__ ctab, const float* __restrict__ stab,
                u16* __restrict__ Qb, u16* __restrict__ Kb, u16* __restrict__ Vtb,
                int K) {
  __shared__ u16 ldsA[128 * 64];
  __shared__ u16 ldsB[128 * 64];
  const int tid = threadIdx.x;
  const int g = blockIdx.y * 24 + blockIdx.x;
  const int xcd = g & 7, gi = g >> 3;       // gi in [0,96)
  const int bm = xcd * 4 + (gi & 3);        // [0,32): 4 bm rows per XCD
  const int bn = gi >> 2;                   // [0,24)
  const int lane = tid & 63, wave = tid >> 6;
  const int wm = wave >> 1, wn = wave & 1;
  const int l16 = lane & 15, quad = lane >> 4;

  // staging: lane -> tile row (p*32 + wave*8 + l>>3), global chunk (l&7)^(l>>3)
  const int srow = lane >> 3;
  const int scol = ((lane & 7) ^ srow) * 8;
  const u16* agb = A + (size_t)(bm * 128 + wave * 8 + srow) * K + scol;
  const u16* bgb = B + (size_t)(bn * 128 + wave * 8 + srow) * K + scol;

  const f32x4 vzero = {0.f, 0.f, 0.f, 0.f};
  f32x4 acc[4][4];
#pragma unroll
  for (int i = 0; i < 4; ++i)
#pragma unroll
    for (int j = 0; j < 4; ++j) acc[i][j] = vzero;

  const int xq = l16 & 7;   // reader swizzle key (= row&7)
  const int NKT = K >> 6;
  for (int kt = 0; kt < NKT; ++kt) {
    __syncthreads();
#pragma unroll
    for (int p = 0; p < 4; ++p) {
      gl_lds16(agb + (size_t)p * 32 * K + kt * 64, &ldsA[(p * 4 + wave) * 512]);
      gl_lds16(bgb + (size_t)p * 32 * K + kt * 64, &ldsB[(p * 4 + wave) * 512]);
    }
    __syncthreads();
#pragma unroll
    for (int ks = 0; ks < 2; ++ks) {
      bf16x8 af[4], bfr[4];
#pragma unroll
      for (int mi = 0; mi < 4; ++mi)
        af[mi] = *(const bf16x8*)&ldsA[(wm * 64 + mi * 16 + l16) * 64 + ((ks * 4 + quad) ^ xq) * 8];
#pragma unroll
      for (int ni = 0; ni < 4; ++ni)
        bfr[ni] = *(const bf16x8*)&ldsB[(wn * 64 + ni * 16 + l16) * 64 + ((ks * 4 + quad) ^ xq) * 8];
#pragma unroll
      for (int mi = 0; mi < 4; ++mi)
#pragma unroll
        for (int ni = 0; ni < 4; ++ni)
          acc[mi][ni] = __builtin_amdgcn_mfma_f32_16x16x32_bf16(af[mi], bfr[ni], acc[mi][ni], 0, 0, 0);
    }
  }

  const int row0 = bm * 128 + wm * 64, col0 = bn * 128 + wn * 64;
  const int sect = bn >> 3;  // 0=Q, 1=K, 2=V

  if (sect < 2) {
    u16* dst = sect == 0 ? Qb : Kb;
    const float mul = sect == 0 ? 0.18033688f : 1.0f;   // 0.125 * log2(e)
#pragma unroll
    for (int mi = 0; mi < 4; ++mi)
#pragma unroll
      for (int ni = 0; ni < 4; ++ni) {
        int col = col0 + ni * 16 + l16;
        int cc = col & 1023;
        int h = cc >> 6, tt = (cc & 63) >> 1;
#pragma unroll
        for (int rr = 0; rr < 4; ++rr) {
          int row = row0 + mi * 16 + quad * 4 + rr;
          int s = row & 2047, bb = row >> 11;
          float x = acc[mi][ni][rr];
          float xo = swap1(x);             // neighbor col's value (DPP, no LDS)
          float x1 = (l16 & 1) ? xo : x;   // even-col element
          float x2 = (l16 & 1) ? x : xo;   // odd-col element
          float cs = ctab[s * 32 + tt], sn = stab[s * 32 + tt];
          float r1 = (x1 * cs - x2 * sn) * mul;
          float r2 = (x1 * sn + x2 * cs) * mul;
          if (!(l16 & 1)) {
            union { u16 h2[2]; unsigned u; } o;
            o.h2[0] = f2bf(r1); o.h2[1] = f2bf(r2);
            *(unsigned*)&dst[((size_t)(bb * 16 + h) * 2048 + s) * 64 + (cc & 63)] = o.u;
          }
        }
      }
  } else {
    // V: per lane, acc[mi][ni][0..3] = 4 consecutive s for fixed col -> 8B store
#pragma unroll
    for (int mi = 0; mi < 4; ++mi)
#pragma unroll
      for (int ni = 0; ni < 4; ++ni) {
        int col = col0 + ni * 16 + l16;
        int cc = col & 1023;
        int h = cc >> 6, d = cc & 63;
        int row = row0 + mi * 16 + quad * 4;
        int s = row & 2047, bb = row >> 11;
        u16x4 o;
        o[0] = f2bf(acc[mi][ni][0]); o[1] = f2bf(acc[mi][ni][1]);
        o[2] = f2bf(acc[mi][ni][2]); o[3] = f2bf(acc[mi][ni][3]);
        *(u16x4*)&Vtb[((size_t)(bb * 16 + h) * 64 + d) * 2048 + s] = o;
      }
  }
}

// ---------------- flash attention v11: QBLK=128, bias C-seed, half-split ----
// R6 lesson: predicated ds_write_b32 does NOT halve DS issues (exec-masked
// instr still issues once) -> P path reverted to R5's plain f2bf + b16 stores.
// New (dependency-structure only, no added instructions):
//  - bias seeds the QK MFMA accumulator (D = QK + C): 16 v_add/tile removed,
//    exp input = sa directly. Masked cols seed -1e30 -> exp2 -> 0.
//  - half-split: {exp+write ni=0,1 -> PV ks=0} {exp+write ni=2,3 -> PV ks=1}.
//    PV ks needs exactly chunks 4ks..4ks+3 = ni=2ks,2ks+1 (wave-local DS
//    in-order guarantees RAW). PV starts 8 exps earlier; VALU||MFMA overlap.
// __launch_bounds__(512,4): VGPR cap 128, no spill (R4: (512,6) spilled).
__global__ __launch_bounds__(512, 4)
void k_attn(const u16* __restrict__ Qb, const u16* __restrict__ Kb, const u16* __restrict__ Vtb,
            const float* __restrict__ rel_bias, const int* __restrict__ mask,
            u16* __restrict__ Ob) {
  __shared__ u16 Ks[2][64 * 64];
  __shared__ u16 Vs[2][64 * 64];
  __shared__ u16 Ps[128 * 64];   // XOR-swizzled like Ks/Vs; wave w owns rows w*16..+15

  const int tid = threadIdx.x;
  const int gid = blockIdx.x;
  const int h = gid & 15, b = (gid >> 4) & 1, qt = gid >> 5;  // qt in [0,16)
  const int bh = b * 16 + h;
  const int lane = tid & 63, w = tid >> 6;                    // w in [0,8)
  const int l16 = lane & 15, quad = lane >> 4;
  const int xq = l16 & 7;   // reader swizzle key (= row&7 for rows ...+l16)

  // Q fragments in registers (rows qt*128 + w*16 + l16), direct global
  bf16x8 qreg[2];
  {
    const u16* qg = Qb + ((size_t)bh * 2048 + qt * 128 + w * 16 + l16) * 64 + quad * 8;
    qreg[0] = *(const bf16x8*)&qg[0];
    qreg[1] = *(const bf16x8*)&qg[32];
  }

  // staging: 8 waves cover 64 rows in one pass; lane -> row w*8 + l>>3,
  // global chunk (l&7)^(l>>3) (pre-swizzled source, linear LDS dest)
  const int srow = lane >> 3;
  const int scol = ((lane & 7) ^ srow) * 8;
  const u16* kgb = Kb + ((size_t)bh * 2048 + w * 8 + srow) * 64 + scol;
  const u16* vgb = Vtb + ((size_t)bh * 64 + w * 8 + srow) * 2048 + scol;

  // bias/mask bases: rows quad*4+rr, col l16 (+ kt0 + ni*16)
  const float* bp[4];
#pragma unroll
  for (int rr = 0; rr < 4; ++rr)
    bp[rr] = rel_bias + ((size_t)h * 2048 + qt * 128 + w * 16 + quad * 4 + rr) * 2048 + l16;
  const int* mbase = mask + b * 2048 + l16;

  const f32x4 vzero = {0.f, 0.f, 0.f, 0.f};
  f32x4 accO[4];
  float ls[4] = {0.f, 0.f, 0.f, 0.f};
#pragma unroll
  for (int ni = 0; ni < 4; ++ni) accO[ni] = vzero;

  // prologue: bias tile 0 (pre-transformed to exp2 domain) + DMA tile 0
  float brc[4][4], brn[4][4];
#pragma unroll
  for (int ni = 0; ni < 4; ++ni) {
    int mk = mbase[ni * 16];
#pragma unroll
    for (int rr = 0; rr < 4; ++rr) {
      float bv = bp[rr][ni * 16];
      brc[ni][rr] = mk ? bv * 1.44269504f - 34.6246810f : -1e30f;
    }
  }
  gl_lds16(kgb, &Ks[0][w * 512]);
  gl_lds16(vgb, &Vs[0][w * 512]);

  for (int t = 0; t < 32; ++t) {
    const int cur = t & 1, nxt = cur ^ 1;
    const int kt0 = t * 64;
    // Single barrier: (a) drains this wave's DMA(t) [issued last iter, covered
    // by tile t-1 compute], (b) all waves done reading buf[nxt] in tile t-1.
    __syncthreads();

    if (t + 1 < 32) {  // issue t+1 DMA + bias: in flight across the WHOLE tile t
      gl_lds16(kgb + (kt0 + 64) * 64, &Ks[nxt][w * 512]);
      gl_lds16(vgb + kt0 + 64,        &Vs[nxt][w * 512]);
#pragma unroll
      for (int ni = 0; ni < 4; ++ni) {
        int mk = mbase[kt0 + 64 + ni * 16];
#pragma unroll
        for (int rr = 0; rr < 4; ++rr) {
          float bv = bp[rr][kt0 + 64 + ni * 16];
          brn[ni][rr] = mk ? bv * 1.44269504f - 34.6246810f : -1e30f;
        }
      }
    }

    // S2 = (Q K^T)*0.125*log2e + bias2, bias seeded as MFMA C-in
    f32x4 sa[4];
#pragma unroll
    for (int ni = 0; ni < 4; ++ni) {
      sa[ni][0] = brc[ni][0]; sa[ni][1] = brc[ni][1];
      sa[ni][2] = brc[ni][2]; sa[ni][3] = brc[ni][3];
    }
    __builtin_amdgcn_s_setprio(1);
#pragma unroll
    for (int ks = 0; ks < 2; ++ks) {
#pragma unroll
      for (int ni = 0; ni < 4; ++ni) {
        bf16x8 kf = *(const bf16x8*)&Ks[cur][(ni * 16 + l16) * 64 + ((ks * 4 + quad) ^ xq) * 8];
        sa[ni] = __builtin_amdgcn_mfma_f32_16x16x32_bf16(qreg[ks], kf, sa[ni], 0, 0, 0);
      }
    }
    __builtin_amdgcn_s_setprio(0);

    // half-split softmax->PV: PV ks consumes exactly the chunks written by
    // ni=2ks,2ks+1 (wave-local rows; DS in-order per wave => RAW safe).
#pragma unroll
    for (int half = 0; half < 2; ++half) {
#pragma unroll
      for (int ni = 2 * half; ni < 2 * half + 2; ++ni) {
#pragma unroll
        for (int rr = 0; rr < 4; ++rr) {
          float p = fexp2(sa[ni][rr]);
          int prow = w * 16 + quad * 4 + rr;
          Ps[prow * 64 + (((ni * 2 + (l16 >> 3)) ^ (prow & 7)) << 3) + (l16 & 7)] = f2bf(p);
          ls[rr] += p;
        }
      }
      bf16x8 pf = *(const bf16x8*)&Ps[(w * 16 + l16) * 64 + ((half * 4 + quad) ^ xq) * 8];
      __builtin_amdgcn_s_setprio(1);
#pragma unroll
      for (int ni = 0; ni < 4; ++ni) {
        bf16x8 vf = *(const bf16x8*)&Vs[cur][(ni * 16 + l16) * 64 + ((half * 4 + quad) ^ xq) * 8];
        accO[ni] = __builtin_amdgcn_mfma_f32_16x16x32_bf16(pf, vf, accO[ni], 0, 0, 0);
      }
      __builtin_amdgcn_s_setprio(0);
    }

    // rotate prefetched bias (t=31: dead values, unused)
#pragma unroll
    for (int ni = 0; ni < 4; ++ni)
#pragma unroll
      for (int rr = 0; rr < 4; ++rr) brc[ni][rr] = brn[ni][rr];
  }

  // reduce l across the 16 lanes holding each row's columns, then write O
#pragma unroll
  for (int rr = 0; rr < 4; ++rr) {
#pragma unroll
    for (int d = 1; d < 16; d <<= 1) ls[rr] += __shfl_xor(ls[rr], d, 16);
  }
#pragma unroll
  for (int rr = 0; rr < 4; ++rr) {
    float inv = 1.f / ls[rr];
    int row = qt * 128 + w * 16 + quad * 4 + rr;
#pragma unroll
    for (int ni = 0; ni < 4; ++ni)
      Ob[(((size_t)b * 2048 + row) * 16 + h) * 64 + ni * 16 + l16] = f2bf(accO[ni][rr] * inv);
  }
}

// ---------------- output GEMM: 128x64 tile, XCD-chunked ---------------------
__global__ __launch_bounds__(256, 4)
void k_gemm_n64(const u16* __restrict__ A, const u16* __restrict__ B,
                const float* __restrict__ bias, float* __restrict__ C,
                int K, int ldc) {
  __shared__ u16 ldsA[128 * 64];
  __shared__ u16 ldsB[64 * 64];
  const int tid = threadIdx.x;
  const int g = blockIdx.y * 16 + blockIdx.x;
  const int xcd = g & 7, gi = g >> 3;       // gi in [0,64)
  const int bm = xcd * 4 + (gi & 3);        // [0,32)
  const int bn = gi >> 2;                   // [0,16)
  const int lane = tid & 63, wave = tid >> 6;
  const int wm = wave >> 1, wn = wave & 1;
  const int l16 = lane & 15, quad = lane >> 4;

  const int srow = lane >> 3;
  const int scol = ((lane & 7) ^ srow) * 8;
  const u16* agb = A + (size_t)(bm * 128 + wave * 8 + srow) * K + scol;
  const u16* bgb = B + (size_t)(bn * 64 + wave * 8 + srow) * K + scol;

  const f32x4 vzero = {0.f, 0.f, 0.f, 0.f};
  f32x4 acc[4][2];
#pragma unroll
  for (int i = 0; i < 4; ++i)
#pragma unroll
    for (int j = 0; j < 2; ++j) acc[i][j] = vzero;

  const int xq = l16 & 7;
  const int NKT = K >> 6;
  for (int kt = 0; kt < NKT; ++kt) {
    __syncthreads();
#pragma unroll
    for (int p = 0; p < 4; ++p)
      gl_lds16(agb + (size_t)p * 32 * K + kt * 64, &ldsA[(p * 4 + wave) * 512]);
#pragma unroll
    for (int p = 0; p < 2; ++p)
      gl_lds16(bgb + (size_t)p * 32 * K + kt * 64, &ldsB[(p * 4 + wave) * 512]);
    __syncthreads();
#pragma unroll
    for (int ks = 0; ks < 2; ++ks) {
      bf16x8 af[4], bfr[2];
#pragma unroll
      for (int mi = 0; mi < 4; ++mi)
        af[mi] = *(const bf16x8*)&ldsA[(wm * 64 + mi * 16 + l16) * 64 + ((ks * 4 + quad) ^ xq) * 8];
#pragma unroll
      for (int ni = 0; ni < 2; ++ni)
        bfr[ni] = *(const bf16x8*)&ldsB[(wn * 32 + ni * 16 + l16) * 64 + ((ks * 4 + quad) ^ xq) * 8];
#pragma unroll
      for (int mi = 0; mi < 4; ++mi)
#pragma unroll
        for (int ni = 0; ni < 2; ++ni)
          acc[mi][ni] = __builtin_amdgcn_mfma_f32_16x16x32_bf16(af[mi], bfr[ni], acc[mi][ni], 0, 0, 0);
    }
  }

  const int row0 = bm * 128 + wm * 64, col0 = bn * 64 + wn * 32;
#pragma unroll
  for (int mi = 0; mi < 4; ++mi)
#pragma unroll
    for (int ni = 0; ni < 2; ++ni) {
      int col = col0 + ni * 16 + l16;
      float badd = bias ? bias[col] : 0.f;
#pragma unroll
      for (int rr = 0; rr < 4; ++rr) {
        int row = row0 + mi * 16 + quad * 4 + rr;
        C[(size_t)row * ldc + col] = acc[mi][ni][rr] + badd;
      }
    }
}

// ---------------- launch ----------------
extern "C" void kernel_launch(void* const* d_in, const int* in_sizes, int n_in,
                              void* d_out, int out_size, void* d_ws, size_t ws_size,
                              hipStream_t stream) {
  (void)in_sizes; (void)n_in; (void)out_size; (void)ws_size;
  const float* hs  = (const float*)d_in[0];
  const int*   msk = (const int*)d_in[1];
  const float* Wq  = (const float*)d_in[2];
  const float* Wk  = (const float*)d_in[3];
  const float* Wv  = (const float*)d_in[4];
  const float* Wo  = (const float*)d_in[5];
  const float* bo  = (const float*)d_in[6];
  const float* rb  = (const float*)d_in[7];
  float* out = (float*)d_out;

  char* ws = (char*)d_ws;
  size_t off = 0;
  auto alloc = [&](size_t n) { char* p = ws + off; off += (n + 255) & ~(size_t)255; return p; };
  u16*   Xb   = (u16*)  alloc(4096UL * 1024 * 2);   // 8 MB (reused as Ob)
  u16*   Wqkv = (u16*)  alloc(3072UL * 1024 * 2);
  u16*   Wob  = (u16*)  alloc(1024UL * 1024 * 2);
  u16*   Qb   = (u16*)  alloc(4096UL * 1024 * 2);
  u16*   Kb   = (u16*)  alloc(4096UL * 1024 * 2);
  u16*   Vtb  = (u16*)  alloc(4096UL * 1024 * 2);
  float* ctab = (float*)alloc(2048UL * 32 * 4);
  float* stab = (float*)alloc(2048UL * 32 * 4);
  u16*   Ob   = Xb;  // Xb dead after fused QKV GEMM (stream-ordered)

  k_convert<<<8448, 256, 0, stream>>>(hs, Wq, Wk, Wv, Wo, Xb, Wqkv, Wob, ctab, stab);
  k_gemm_qkv<<<dim3(24, 32), 256, 0, stream>>>(Xb, Wqkv, ctab, stab, Qb, Kb, Vtb, 1024);
  k_attn<<<512, 512, 0, stream>>>(Qb, Kb, Vtb, rb, msk, Ob);
  k_gemm_n64<<<dim3(16, 32), 256, 0, stream>>>(Ob, Wob, bo, out, 1024, 1024);
}